// Round 10
// baseline (236.398 us; speedup 1.0000x reference)
//
#include <hip/hip_runtime.h>
#include <math.h>

// LipsNet R10. B=8192, D_IN=256, H=256, D_OUT=64.
// k0: 32x32x16 A-frag packs (W2T32, W1T32) + 32x32 B-pack (W3B32) for k2;
//     hi/lo 16x16 A-frag packs for k1 (R7-validated).
// k1: split-bf16 MFMA forward, R8-verbatim (best measured ~59 us).
// k2: Jacobian on v_mfma_f32_32x32x16_bf16; 2 samples/block, 512 thr, grid 4096.
//     A1^T = W2T @ (W3 .* r2)^T ; M^T = W1T @ (A1^T .* r1); 17% lower MFMA floor,
//     ~half the instruction/frag-traffic overhead vs 16x16.
//
// 32x32x16 layouts (A/B: generalization of R2-validated 16x16 pattern; C/D guide-verified):
//   A[m][k]: m = lane&31, k = (lane>>5)*8 + i
//   B[k][n]: n = lane&31, k = (lane>>5)*8 + i
//   C/D:     col = lane&31, row = (reg&3) + 8*(reg>>2) + 4*(lane>>5)   (16 regs)

typedef float  f32x4  __attribute__((ext_vector_type(4)));
typedef float  f32x16 __attribute__((ext_vector_type(16)));
typedef short  bf16x8 __attribute__((ext_vector_type(8)));
typedef unsigned int   uint;
typedef unsigned short ushort;
typedef unsigned char  uchar;
typedef uint   u32x4  __attribute__((ext_vector_type(4)));
typedef uint   u32x2  __attribute__((ext_vector_type(2)));

// ws byte offsets
#define W2T32_OFF 0u        // 8mt x 16kt x 64l x 16B = 131072  (recycled slot)
#define W1T32_OFF 131072u   // 131072                            (recycled slot)
#define W3A_OFF   262144u   // 32768 (k1 layer-3 hi A-frags, 16x16)
#define F_OFF     294912u   // 8192x64 fp32 = 2097152
#define R1_OFF    2392064u  // 8192x256 u8 = 2097152
#define R2_OFF    4489216u  // 2097152
#define W1AH_OFF  6586368u  // 131072
#define W1AL_OFF  6717440u  // 131072
#define W2AH_OFF  6848512u  // 131072
#define W2AL_OFF  6979584u  // 131072
#define W3AL_OFF  7110656u  // 32768
#define W3B32_OFF 7143424u  // 2nt x 16kt x 64l x 16B = 32768
// total 7176192 B

__device__ __forceinline__ ushort f2bf(float f) {
    uint u = __builtin_bit_cast(uint, f);
    u += 0x7FFFu + ((u >> 16) & 1u);          // RNE
    return (ushort)(u >> 16);
}
__device__ __forceinline__ float bf2f(ushort h) {
    uint u = ((uint)h) << 16;
    return __builtin_bit_cast(float, u);
}
// halfword and-mask from two mask bytes of u at bit positions sh, sh+8
__device__ __forceinline__ uint hm2(uint u, int sh) {
    return (((u >> sh) & 0xFFu)   ? 0xFFFFu     : 0u) |
           (((u >> sh) & 0xFF00u) ? 0xFFFF0000u : 0u);
}

// ---------------- k0: weight prep ----------------
__global__ __launch_bounds__(256) void k0_prep(
    const float* __restrict__ W1, const float* __restrict__ W2,
    const float* __restrict__ W3, char* __restrict__ ws)
{
    const int id = blockIdx.x * 256 + threadIdx.x;
    if (id >= 36864) return;

    if (id < 16384) {
        // 32x32 A-frag transposed gathers for k2: A[m][k] = W[k][m]
        const int fid = id & 8191;
        const int l = fid & 63, kt = (fid >> 6) & 15, mt = fid >> 10;
        const int m = mt * 32 + (l & 31);
        const int kb = kt * 16 + (l >> 5) * 8;
        const float* M = (id < 8192) ? W2 : W1;
        const uint dstoff = (id < 8192) ? W2T32_OFF : W1T32_OFF;
        ushort h[8];
        #pragma unroll
        for (int i = 0; i < 8; ++i) h[i] = f2bf(M[(kb + i) * 256 + m]);
        u32x4 v;
        v.x = (uint)h[0] | ((uint)h[1] << 16);
        v.y = (uint)h[2] | ((uint)h[3] << 16);
        v.z = (uint)h[4] | ((uint)h[5] << 16);
        v.w = (uint)h[6] | ((uint)h[7] << 16);
        ((u32x4*)(ws + dstoff))[fid] = v;
        return;
    }
    if (id >= 34816) {
        // W3B32: B[k=d][n=j] = W3[j][d]
        const int fid = id - 34816;               // 0..2047
        const int l = fid & 63, kt = (fid >> 6) & 15, nt = fid >> 10;
        const int j = nt * 32 + (l & 31);
        const int d0 = kt * 16 + (l >> 5) * 8;
        const float* p = W3 + j * 256 + d0;
        ushort h[8];
        #pragma unroll
        for (int i = 0; i < 8; ++i) h[i] = f2bf(p[i]);
        u32x4 v;
        v.x = (uint)h[0] | ((uint)h[1] << 16);
        v.y = (uint)h[2] | ((uint)h[3] << 16);
        v.z = (uint)h[4] | ((uint)h[5] << 16);
        v.w = (uint)h[6] | ((uint)h[7] << 16);
        ((u32x4*)(ws + W3B32_OFF))[fid] = v;
        return;
    }

    // hi/lo 16x16 A-frag pairs (row-major gathers) for k1 forward (R7-validated)
    const float* M;
    uint hiOff, loOff;
    int fid;
    if (id < 18432)      { fid = id - 16384; M = W3; hiOff = W3A_OFF;  loOff = W3AL_OFF; }
    else if (id < 26624) { fid = id - 18432; M = W1; hiOff = W1AH_OFF; loOff = W1AL_OFF; }
    else                 { fid = id - 26624; M = W2; hiOff = W2AH_OFF; loOff = W2AL_OFF; }
    const int l = fid & 63, ks = (fid >> 6) & 7, rb = fid >> 9;
    const int m = l & 15, q = l >> 4;
    const int k0 = ks * 32 + q * 8;
    const float* p = M + (rb * 16 + m) * 256 + k0;
    ushort hh[8], ll[8];
    #pragma unroll
    for (int i = 0; i < 8; ++i) {
        const float v = p[i];
        const ushort h = f2bf(v);
        hh[i] = h;
        ll[i] = f2bf(v - bf2f(h));     // residual (exact subtraction)
    }
    u32x4 vh, vl;
    vh.x = (uint)hh[0] | ((uint)hh[1] << 16);
    vh.y = (uint)hh[2] | ((uint)hh[3] << 16);
    vh.z = (uint)hh[4] | ((uint)hh[5] << 16);
    vh.w = (uint)hh[6] | ((uint)hh[7] << 16);
    vl.x = (uint)ll[0] | ((uint)ll[1] << 16);
    vl.y = (uint)ll[2] | ((uint)ll[3] << 16);
    vl.z = (uint)ll[4] | ((uint)ll[5] << 16);
    vl.w = (uint)ll[6] | ((uint)ll[7] << 16);
    ((u32x4*)(ws + hiOff))[fid] = vh;
    ((u32x4*)(ws + loOff))[fid] = vl;
}

// ---------------- k1: split-bf16 MFMA forward, 16 samples/block, 512 thr (R8-verbatim) ----------------
#define FWD_KLOOP(INOFF, HIOFF, LOOFF, NRB, RBOF, ACC)                             \
    {                                                                              \
        const bf16x8* WH = (const bf16x8*)(ws + (HIOFF));                          \
        const bf16x8* WL = (const bf16x8*)(ws + (LOOFF));                          \
        _Pragma("unroll")                                                          \
        for (int rr = 0; rr < (NRB); ++rr) ACC[rr] = (f32x4){0.f, 0.f, 0.f, 0.f};  \
        _Pragma("unroll")                                                          \
        for (int ks = 0; ks < 8; ++ks) {                                           \
            const int kk = ks * 32 + q * 8;                                        \
            float av[8];                                                           \
            *(f32x4*)&av[0] = *(const f32x4*)&SB[(INOFF) + m * 260 + kk];          \
            *(f32x4*)&av[4] = *(const f32x4*)&SB[(INOFF) + m * 260 + kk + 4];      \
            uint hw[4], lw[4];                                                     \
            _Pragma("unroll")                                                      \
            for (int pp = 0; pp < 4; ++pp) {                                       \
                const float a0 = av[2 * pp], a1 = av[2 * pp + 1];                  \
                const ushort h0 = f2bf(a0), h1 = f2bf(a1);                         \
                const float r0 = a0 - bf2f(h0), r1 = a1 - bf2f(h1);                \
                hw[pp] = (uint)h0 | ((uint)h1 << 16);                              \
                lw[pp] = (uint)f2bf(r0) | ((uint)f2bf(r1) << 16);                  \
            }                                                                      \
            const bf16x8 bhi = __builtin_bit_cast(bf16x8, (u32x4){hw[0], hw[1], hw[2], hw[3]}); \
            const bf16x8 blo = __builtin_bit_cast(bf16x8, (u32x4){lw[0], lw[1], lw[2], lw[3]}); \
            _Pragma("unroll")                                                      \
            for (int rr = 0; rr < (NRB); ++rr) {                                   \
                const int rb = (RBOF) + rr;                                        \
                const bf16x8 ah = WH[(rb * 8 + ks) * 64 + l];                      \
                const bf16x8 al = WL[(rb * 8 + ks) * 64 + l];                      \
                ACC[rr] = __builtin_amdgcn_mfma_f32_16x16x32_bf16(ah, bhi, ACC[rr], 0, 0, 0); \
                ACC[rr] = __builtin_amdgcn_mfma_f32_16x16x32_bf16(al, bhi, ACC[rr], 0, 0, 0); \
                ACC[rr] = __builtin_amdgcn_mfma_f32_16x16x32_bf16(ah, blo, ACC[rr], 0, 0, 0); \
            }                                                                      \
        }                                                                          \
    }

__global__ __launch_bounds__(512) void k1_forward(
    const float* __restrict__ x,
    const float* __restrict__ b1, const float* __restrict__ b2,
    const float* __restrict__ b3, char* __restrict__ ws)
{
    __shared__ float SB[2 * 4160];   // [2][16 samples][260 fp32]; buf0: x then h2, buf1: h1
    const int t = threadIdx.x, w = t >> 6, l = t & 63;
    const int m = l & 15, q = l >> 4;
    const int g0 = blockIdx.x * 16;
    float* fws = (float*)(ws + F_OFF);
    uchar* r1g = (uchar*)(ws + R1_OFF);
    uchar* r2g = (uchar*)(ws + R2_OFF);

    {
        const f32x4* X4 = (const f32x4*)x;
        #pragma unroll
        for (int i = 0; i < 2; ++i) {
            const int idx = t + 512 * i;            // 0..1023
            const int g = idx >> 6, dq = idx & 63;
            *(f32x4*)&SB[g * 260 + dq * 4] = X4[(size_t)(g0 + g) * 64 + dq];
        }
    }
    __syncthreads();

    f32x4 acc[2];

    // ---- layer 1
    FWD_KLOOP(0, W1AH_OFF, W1AL_OFF, 2, 2 * w, acc)
    #pragma unroll
    for (int rr = 0; rr < 2; ++rr) {
        const int i0 = (2 * w + rr) * 16 + q * 4;
        const float4 bv = *(const float4*)(b1 + i0);
        const float v0 = acc[rr].x + bv.x, v1 = acc[rr].y + bv.y;
        const float v2 = acc[rr].z + bv.z, v3 = acc[rr].w + bv.w;
        const uint mv = (v0 > 0.f ? 1u : 0u) | (v1 > 0.f ? 0x100u : 0u) |
                        (v2 > 0.f ? 0x10000u : 0u) | (v3 > 0.f ? 0x1000000u : 0u);
        *(uint*)(r1g + (size_t)(g0 + m) * 256 + i0) = mv;
        const f32x4 rv = {fmaxf(v0, 0.f), fmaxf(v1, 0.f), fmaxf(v2, 0.f), fmaxf(v3, 0.f)};
        *(f32x4*)&SB[4160 + m * 260 + i0] = rv;
    }
    __syncthreads();

    // ---- layer 2
    FWD_KLOOP(4160, W2AH_OFF, W2AL_OFF, 2, 2 * w, acc)
    #pragma unroll
    for (int rr = 0; rr < 2; ++rr) {
        const int i0 = (2 * w + rr) * 16 + q * 4;
        const float4 bv = *(const float4*)(b2 + i0);
        const float v0 = acc[rr].x + bv.x, v1 = acc[rr].y + bv.y;
        const float v2 = acc[rr].z + bv.z, v3 = acc[rr].w + bv.w;
        const uint mv = (v0 > 0.f ? 1u : 0u) | (v1 > 0.f ? 0x100u : 0u) |
                        (v2 > 0.f ? 0x10000u : 0u) | (v3 > 0.f ? 0x1000000u : 0u);
        *(uint*)(r2g + (size_t)(g0 + m) * 256 + i0) = mv;
        const f32x4 rv = {fmaxf(v0, 0.f), fmaxf(v1, 0.f), fmaxf(v2, 0.f), fmaxf(v3, 0.f)};
        *(f32x4*)&SB[m * 260 + i0] = rv;
    }
    __syncthreads();

    // ---- layer 3: waves 0..3
    if (w < 4) {
        FWD_KLOOP(0, W3A_OFF, W3AL_OFF, 1, w, acc)
        const int j0 = w * 16 + q * 4;
        const float4 bv = *(const float4*)(b3 + j0);
        const f32x4 ov = {acc[0].x + bv.x, acc[0].y + bv.y, acc[0].z + bv.z, acc[0].w + bv.w};
        *(f32x4*)(fws + (size_t)(g0 + m) * 64 + j0) = ov;
    }
}

// ---------------- k2: Jacobian (32x32x16 MFMA), 2 samples/block, 512 thr ----------------
__global__ __launch_bounds__(512, 2) void k2_jac(
    const char* __restrict__ ws, const float* __restrict__ kp,
    float* __restrict__ out)
{
    __shared__ char Buf[65536];   // [0,32K): W3 B-frags (GEMM1), then Vh[0]; [32K,64K): Vh[1]
    __shared__ uint r1u[2][64], r2u[2][64];
    __shared__ float red[2][8];

    const int t = threadIdx.x, w = t >> 6, l = t & 63;
    const int n31 = l & 31, q5 = l >> 5;
    const int b = blockIdx.x;

    if (t < 128) {
        const int s = t >> 6, i = t & 63;
        r1u[s][i] = ((const uint*)(ws + R1_OFF))[(size_t)(b * 2 + s) * 64 + i];
        r2u[s][i] = ((const uint*)(ws + R2_OFF))[(size_t)(b * 2 + s) * 64 + i];
    }
    // stage unmasked W3 B-frags into Buf[0..32K)
    {
        const u32x4* src = (const u32x4*)(ws + W3B32_OFF);
        u32x4* dst = (u32x4*)Buf;
        #pragma unroll
        for (int ii = 0; ii < 4; ++ii) dst[t + 512 * ii] = src[t + 512 * ii];
    }
    __syncthreads();

    // ---- GEMM1: A1^T = W2T @ (W3 .* r2)^T ; wave w owns c-tile w (M-dim), all j (2 nt), both s
    f32x16 acc[2][2];
    #pragma unroll
    for (int s = 0; s < 2; ++s)
        #pragma unroll
        for (int nt = 0; nt < 2; ++nt)
            #pragma unroll
            for (int r = 0; r < 16; ++r) acc[s][nt][r] = 0.f;

    {
        const bf16x8* W2T32 = (const bf16x8*)(ws + W2T32_OFF);
        const u32x4* Wb = (const u32x4*)Buf;
        #pragma unroll 1
        for (int kt = 0; kt < 16; ++kt) {
            const bf16x8 a = W2T32[(w * 16 + kt) * 64 + l];
            const int du = kt * 4 + q5 * 2;         // r2 word idx for d0 = kt*16 + q5*8
            uint mw[2][4];
            #pragma unroll
            for (int s = 0; s < 2; ++s) {
                const uint u0 = r2u[s][du], u1 = r2u[s][du + 1];
                mw[s][0] = hm2(u0, 0);  mw[s][1] = hm2(u0, 16);
                mw[s][2] = hm2(u1, 0);  mw[s][3] = hm2(u1, 16);
            }
            #pragma unroll
            for (int nt = 0; nt < 2; ++nt) {
                const u32x4 braw = Wb[(nt * 16 + kt) * 64 + l];
                #pragma unroll
                for (int s = 0; s < 2; ++s) {
                    u32x4 v;
                    v.x = braw.x & mw[s][0];
                    v.y = braw.y & mw[s][1];
                    v.z = braw.z & mw[s][2];
                    v.w = braw.w & mw[s][3];
                    const bf16x8 bb = __builtin_bit_cast(bf16x8, v);
                    acc[s][nt] = __builtin_amdgcn_mfma_f32_32x32x16_bf16(a, bb, acc[s][nt], 0, 0, 0);
                }
            }
        }
    }
    __syncthreads();   // all W3-frag reads done before Vh[0] overlay

    // ---- Phase C: Vh[s][j][c] = A1^T[c][j] * r1[c] (bf16, XOR-swizzled, b64 writes)
    //      C/D: c = w*32 + 8*(r>>2) + 4*q5 + (r&3), j = nt*32 + n31
    {
        ushort* Vh = (ushort*)Buf;
        #pragma unroll
        for (int s = 0; s < 2; ++s)
            #pragma unroll
            for (int nt = 0; nt < 2; ++nt) {
                const int j = nt * 32 + n31;
                const int sw = (j & 7) << 3;
                #pragma unroll
                for (int g = 0; g < 4; ++g) {
                    const int c0 = w * 32 + g * 8 + 4 * q5;
                    const uint mu = r1u[s][c0 >> 2];
                    const float v0 = (mu & 0xFFu)       ? acc[s][nt][4 * g + 0] : 0.f;
                    const float v1 = (mu & 0xFF00u)     ? acc[s][nt][4 * g + 1] : 0.f;
                    const float v2 = (mu & 0xFF0000u)   ? acc[s][nt][4 * g + 2] : 0.f;
                    const float v3 = (mu & 0xFF000000u) ? acc[s][nt][4 * g + 3] : 0.f;
                    u32x2 p;
                    p.x = (uint)f2bf(v0) | ((uint)f2bf(v1) << 16);
                    p.y = (uint)f2bf(v2) | ((uint)f2bf(v3) << 16);
                    *(u32x2*)&Vh[s * 16384 + j * 256 + (c0 ^ sw)] = p;
                }
            }
    }
    __syncthreads();

    // ---- GEMM2: M^T = W1T @ (Vh as B) ; wave w owns e'-tile w, all j, both s
    f32x16 acc2[2][2];
    #pragma unroll
    for (int s = 0; s < 2; ++s)
        #pragma unroll
        for (int nt = 0; nt < 2; ++nt)
            #pragma unroll
            for (int r = 0; r < 16; ++r) acc2[s][nt][r] = 0.f;

    {
        const bf16x8* W1T32 = (const bf16x8*)(ws + W1T32_OFF);
        const ushort* Vh = (const ushort*)Buf;
        #pragma unroll 1
        for (int kt = 0; kt < 16; ++kt) {
            const bf16x8 a = W1T32[(w * 16 + kt) * 64 + l];
            const int c0 = kt * 16 + q5 * 8;
            #pragma unroll
            for (int nt = 0; nt < 2; ++nt) {
                const int j = nt * 32 + n31;
                const int idx = j * 256 + (c0 ^ ((j & 7) << 3));
                #pragma unroll
                for (int s = 0; s < 2; ++s) {
                    const bf16x8 bb = *(const bf16x8*)&Vh[s * 16384 + idx];
                    acc2[s][nt] = __builtin_amdgcn_mfma_f32_32x32x16_bf16(a, bb, acc2[s][nt], 0, 0, 0);
                }
            }
        }
    }

    // ---- reduce ||M_s||_F^2
    {
        float ps0 = 0.f, ps1 = 0.f;
        #pragma unroll
        for (int nt = 0; nt < 2; ++nt)
            #pragma unroll
            for (int r = 0; r < 16; ++r) {
                ps0 = fmaf(acc2[0][nt][r], acc2[0][nt][r], ps0);
                ps1 = fmaf(acc2[1][nt][r], acc2[1][nt][r], ps1);
            }
        #pragma unroll
        for (int off = 32; off > 0; off >>= 1) {
            ps0 += __shfl_down(ps0, off, 64);
            ps1 += __shfl_down(ps1, off, 64);
        }
        if (l == 0) { red[0][w] = ps0; red[1][w] = ps1; }
    }
    __syncthreads();

    if (t < 128) {
        const int s = t >> 6, j = t & 63;
        float S = 0.f;
        #pragma unroll
        for (int i = 0; i < 8; ++i) S += red[s][i];
        const float* fws = (const float*)(ws + F_OFF);
        const float f = fws[(size_t)(b * 2 + s) * 64 + j];
        const float kv = kp[0];
        const float ksp = fmaxf(kv, 0.0f) + log1pf(expf(-fabsf(kv)));
        out[(size_t)(b * 2 + s) * 64 + j] = tanhf(ksp * f / (sqrtf(S) + 1e-4f));
    }
}

extern "C" void kernel_launch(void* const* d_in, const int* in_sizes, int n_in,
                              void* d_out, int out_size, void* d_ws, size_t ws_size,
                              hipStream_t stream) {
    const float* x  = (const float*)d_in[0];
    const float* W1 = (const float*)d_in[1];
    const float* b1 = (const float*)d_in[2];
    const float* W2 = (const float*)d_in[3];
    const float* b2 = (const float*)d_in[4];
    const float* W3 = (const float*)d_in[5];
    const float* b3 = (const float*)d_in[6];
    const float* kp = (const float*)d_in[7];
    char* ws = (char*)d_ws;

    k0_prep<<<144, 256, 0, stream>>>(W1, W2, W3, ws);
    k1_forward<<<512, 512, 0, stream>>>(x, b1, b2, b3, ws);
    k2_jac<<<4096, 512, 0, stream>>>(ws, kp, (float*)d_out);
}

// Round 11
// 211.755 us; speedup vs baseline: 1.1164x; 1.1164x over previous
//
#include <hip/hip_runtime.h>
#include <math.h>

// LipsNet R11. B=8192, D_IN=256, H=256, D_OUT=64.
// k0: weight frags (R4/R7-validated layouts).
// k1: split-bf16 MFMA forward, R8-verbatim.
// k2: Jacobian, S=1 sample/block, 256 thr, grid 8192, Phase-A pre-masked W3 in LDS
//     (R8's low-VALU masking) + 33 KB LDS -> 4 blocks/CU = 4 waves/SIMD (2x R8 TLP).
//     The one untried cell: R9's occupancy with R8's mask structure.
//
// MFMA 16x16x32 layouts (validated R2/R4):
//   A[m][k]: m = lane&15, k = (lane>>4)*8 + i
//   B[k][n]: n = lane&15, k = (lane>>4)*8 + i
//   C/D:     col = lane&15, row = (lane>>4)*4 + reg

typedef float  f32x4  __attribute__((ext_vector_type(4)));
typedef short  bf16x8 __attribute__((ext_vector_type(8)));
typedef unsigned int   uint;
typedef unsigned short ushort;
typedef unsigned char  uchar;
typedef uint   u32x4  __attribute__((ext_vector_type(4)));
typedef uint   u32x2  __attribute__((ext_vector_type(2)));

// ws byte offsets
#define W2TA_OFF 0u        // 16rb x 8ks x 64l x 16B = 131072
#define W1TA_OFF 131072u   // 131072
#define W3A_OFF  262144u   // 32768 (k2 B-source AND k1 layer-3 hi A-frags)
#define F_OFF    294912u   // 8192x64 fp32 = 2097152
#define R1_OFF   2392064u  // 8192x256 u8 = 2097152
#define R2_OFF   4489216u  // 2097152
#define W1AH_OFF 6586368u  // 131072
#define W1AL_OFF 6717440u  // 131072
#define W2AH_OFF 6848512u  // 131072
#define W2AL_OFF 6979584u  // 131072
#define W3AL_OFF 7110656u  // 32768
// total 7143424 B

__device__ __forceinline__ ushort f2bf(float f) {
    uint u = __builtin_bit_cast(uint, f);
    u += 0x7FFFu + ((u >> 16) & 1u);          // RNE
    return (ushort)(u >> 16);
}
__device__ __forceinline__ float bf2f(ushort h) {
    uint u = ((uint)h) << 16;
    return __builtin_bit_cast(float, u);
}
// halfword and-mask from two mask bytes of u at bit positions sh, sh+8
__device__ __forceinline__ uint hm2(uint u, int sh) {
    return (((u >> sh) & 0xFFu)   ? 0xFFFFu     : 0u) |
           (((u >> sh) & 0xFF00u) ? 0xFFFF0000u : 0u);
}

// ---------------- k0: weight prep (R7-validated) ----------------
__global__ __launch_bounds__(256) void k0_prep(
    const float* __restrict__ W1, const float* __restrict__ W2,
    const float* __restrict__ W3, char* __restrict__ ws)
{
    const int id = blockIdx.x * 256 + threadIdx.x;
    if (id >= 34816) return;

    if (id < 16384) {
        // transposed A-frag gathers for k2
        const int fid = id & 8191;
        const int l = fid & 63, ks = (fid >> 6) & 7, rb = fid >> 9;
        const int m = l & 15, q = l >> 4;
        const int k0 = ks * 32 + q * 8;
        const float* M = (id < 8192) ? W2 : W1;
        const uint dstoff = (id < 8192) ? W2TA_OFF : W1TA_OFF;
        const int n = rb * 16 + m;
        ushort h[8];
        #pragma unroll
        for (int i = 0; i < 8; ++i) h[i] = f2bf(M[(k0 + i) * 256 + n]);
        u32x4 v;
        v.x = (uint)h[0] | ((uint)h[1] << 16);
        v.y = (uint)h[2] | ((uint)h[3] << 16);
        v.z = (uint)h[4] | ((uint)h[5] << 16);
        v.w = (uint)h[6] | ((uint)h[7] << 16);
        ((u32x4*)(ws + dstoff))[fid] = v;
        return;
    }

    // hi/lo A-frag pairs (row-major gathers) for k1 forward
    const float* M;
    uint hiOff, loOff;
    int fid;
    if (id < 18432)      { fid = id - 16384; M = W3; hiOff = W3A_OFF;  loOff = W3AL_OFF; }
    else if (id < 26624) { fid = id - 18432; M = W1; hiOff = W1AH_OFF; loOff = W1AL_OFF; }
    else                 { fid = id - 26624; M = W2; hiOff = W2AH_OFF; loOff = W2AL_OFF; }
    const int l = fid & 63, ks = (fid >> 6) & 7, rb = fid >> 9;
    const int m = l & 15, q = l >> 4;
    const int k0 = ks * 32 + q * 8;
    const float* p = M + (rb * 16 + m) * 256 + k0;
    ushort hh[8], ll[8];
    #pragma unroll
    for (int i = 0; i < 8; ++i) {
        const float v = p[i];
        const ushort h = f2bf(v);
        hh[i] = h;
        ll[i] = f2bf(v - bf2f(h));     // residual (exact subtraction)
    }
    u32x4 vh, vl;
    vh.x = (uint)hh[0] | ((uint)hh[1] << 16);
    vh.y = (uint)hh[2] | ((uint)hh[3] << 16);
    vh.z = (uint)hh[4] | ((uint)hh[5] << 16);
    vh.w = (uint)hh[6] | ((uint)hh[7] << 16);
    vl.x = (uint)ll[0] | ((uint)ll[1] << 16);
    vl.y = (uint)ll[2] | ((uint)ll[3] << 16);
    vl.z = (uint)ll[4] | ((uint)ll[5] << 16);
    vl.w = (uint)ll[6] | ((uint)ll[7] << 16);
    ((u32x4*)(ws + hiOff))[fid] = vh;
    ((u32x4*)(ws + loOff))[fid] = vl;
}

// ---------------- k1: split-bf16 MFMA forward, 16 samples/block, 512 thr (R8-verbatim) ----------------
#define FWD_KLOOP(INOFF, HIOFF, LOOFF, NRB, RBOF, ACC)                             \
    {                                                                              \
        const bf16x8* WH = (const bf16x8*)(ws + (HIOFF));                          \
        const bf16x8* WL = (const bf16x8*)(ws + (LOOFF));                          \
        _Pragma("unroll")                                                          \
        for (int rr = 0; rr < (NRB); ++rr) ACC[rr] = (f32x4){0.f, 0.f, 0.f, 0.f};  \
        _Pragma("unroll")                                                          \
        for (int ks = 0; ks < 8; ++ks) {                                           \
            const int kk = ks * 32 + q * 8;                                        \
            float av[8];                                                           \
            *(f32x4*)&av[0] = *(const f32x4*)&SB[(INOFF) + m * 260 + kk];          \
            *(f32x4*)&av[4] = *(const f32x4*)&SB[(INOFF) + m * 260 + kk + 4];      \
            uint hw[4], lw[4];                                                     \
            _Pragma("unroll")                                                      \
            for (int pp = 0; pp < 4; ++pp) {                                       \
                const float a0 = av[2 * pp], a1 = av[2 * pp + 1];                  \
                const ushort h0 = f2bf(a0), h1 = f2bf(a1);                         \
                const float r0 = a0 - bf2f(h0), r1 = a1 - bf2f(h1);                \
                hw[pp] = (uint)h0 | ((uint)h1 << 16);                              \
                lw[pp] = (uint)f2bf(r0) | ((uint)f2bf(r1) << 16);                  \
            }                                                                      \
            const bf16x8 bhi = __builtin_bit_cast(bf16x8, (u32x4){hw[0], hw[1], hw[2], hw[3]}); \
            const bf16x8 blo = __builtin_bit_cast(bf16x8, (u32x4){lw[0], lw[1], lw[2], lw[3]}); \
            _Pragma("unroll")                                                      \
            for (int rr = 0; rr < (NRB); ++rr) {                                   \
                const int rb = (RBOF) + rr;                                        \
                const bf16x8 ah = WH[(rb * 8 + ks) * 64 + l];                      \
                const bf16x8 al = WL[(rb * 8 + ks) * 64 + l];                      \
                ACC[rr] = __builtin_amdgcn_mfma_f32_16x16x32_bf16(ah, bhi, ACC[rr], 0, 0, 0); \
                ACC[rr] = __builtin_amdgcn_mfma_f32_16x16x32_bf16(al, bhi, ACC[rr], 0, 0, 0); \
                ACC[rr] = __builtin_amdgcn_mfma_f32_16x16x32_bf16(ah, blo, ACC[rr], 0, 0, 0); \
            }                                                                      \
        }                                                                          \
    }

__global__ __launch_bounds__(512) void k1_forward(
    const float* __restrict__ x,
    const float* __restrict__ b1, const float* __restrict__ b2,
    const float* __restrict__ b3, char* __restrict__ ws)
{
    __shared__ float SB[2 * 4160];   // [2][16 samples][260 fp32]; buf0: x then h2, buf1: h1
    const int t = threadIdx.x, w = t >> 6, l = t & 63;
    const int m = l & 15, q = l >> 4;
    const int g0 = blockIdx.x * 16;
    float* fws = (float*)(ws + F_OFF);
    uchar* r1g = (uchar*)(ws + R1_OFF);
    uchar* r2g = (uchar*)(ws + R2_OFF);

    {
        const f32x4* X4 = (const f32x4*)x;
        #pragma unroll
        for (int i = 0; i < 2; ++i) {
            const int idx = t + 512 * i;            // 0..1023
            const int g = idx >> 6, dq = idx & 63;
            *(f32x4*)&SB[g * 260 + dq * 4] = X4[(size_t)(g0 + g) * 64 + dq];
        }
    }
    __syncthreads();

    f32x4 acc[2];

    // ---- layer 1
    FWD_KLOOP(0, W1AH_OFF, W1AL_OFF, 2, 2 * w, acc)
    #pragma unroll
    for (int rr = 0; rr < 2; ++rr) {
        const int i0 = (2 * w + rr) * 16 + q * 4;
        const float4 bv = *(const float4*)(b1 + i0);
        const float v0 = acc[rr].x + bv.x, v1 = acc[rr].y + bv.y;
        const float v2 = acc[rr].z + bv.z, v3 = acc[rr].w + bv.w;
        const uint mv = (v0 > 0.f ? 1u : 0u) | (v1 > 0.f ? 0x100u : 0u) |
                        (v2 > 0.f ? 0x10000u : 0u) | (v3 > 0.f ? 0x1000000u : 0u);
        *(uint*)(r1g + (size_t)(g0 + m) * 256 + i0) = mv;
        const f32x4 rv = {fmaxf(v0, 0.f), fmaxf(v1, 0.f), fmaxf(v2, 0.f), fmaxf(v3, 0.f)};
        *(f32x4*)&SB[4160 + m * 260 + i0] = rv;
    }
    __syncthreads();

    // ---- layer 2
    FWD_KLOOP(4160, W2AH_OFF, W2AL_OFF, 2, 2 * w, acc)
    #pragma unroll
    for (int rr = 0; rr < 2; ++rr) {
        const int i0 = (2 * w + rr) * 16 + q * 4;
        const float4 bv = *(const float4*)(b2 + i0);
        const float v0 = acc[rr].x + bv.x, v1 = acc[rr].y + bv.y;
        const float v2 = acc[rr].z + bv.z, v3 = acc[rr].w + bv.w;
        const uint mv = (v0 > 0.f ? 1u : 0u) | (v1 > 0.f ? 0x100u : 0u) |
                        (v2 > 0.f ? 0x10000u : 0u) | (v3 > 0.f ? 0x1000000u : 0u);
        *(uint*)(r2g + (size_t)(g0 + m) * 256 + i0) = mv;
        const f32x4 rv = {fmaxf(v0, 0.f), fmaxf(v1, 0.f), fmaxf(v2, 0.f), fmaxf(v3, 0.f)};
        *(f32x4*)&SB[m * 260 + i0] = rv;
    }
    __syncthreads();

    // ---- layer 3: waves 0..3
    if (w < 4) {
        FWD_KLOOP(0, W3A_OFF, W3AL_OFF, 1, w, acc)
        const int j0 = w * 16 + q * 4;
        const float4 bv = *(const float4*)(b3 + j0);
        const f32x4 ov = {acc[0].x + bv.x, acc[0].y + bv.y, acc[0].z + bv.z, acc[0].w + bv.w};
        *(f32x4*)(fws + (size_t)(g0 + m) * 64 + j0) = ov;
    }
}

// ---------------- k2: Jacobian, 1 sample/block, 256 thr, Phase-A pre-masked ----------------
__global__ __launch_bounds__(256, 4) void k2_jac(
    const char* __restrict__ ws, const float* __restrict__ kp,
    float* __restrict__ out)
{
    __shared__ char Buf[32768];            // Phase A: masked W3 B-frags; then Vh overlay
    __shared__ uint r1u[64], r2u[64];
    __shared__ float red[4];

    const int t = threadIdx.x, w = t >> 6, l = t & 63;
    const int m = l & 15, q = l >> 4;
    const int b = blockIdx.x;

    if (t < 64)       r1u[t]      = ((const uint*)(ws + R1_OFF))[(size_t)b * 64 + t];
    else if (t < 128) r2u[t - 64] = ((const uint*)(ws + R2_OFF))[(size_t)b * 64 + (t - 64)];
    __syncthreads();

    // ---- Phase A: build Bf1 = (W3 .* r2)^T B-frags (8 frag-units per wave)
    {
        const u32x4* W3Av = (const u32x4*)(ws + W3A_OFF);
        u32x4* BufV = (u32x4*)Buf;
        #pragma unroll
        for (int ii = 0; ii < 8; ++ii) {
            const int id = w * 8 + ii;                // 0..31: cb = id>>3, ks = id&7
            const int ks = id & 7;
            u32x4 v = W3Av[id * 64 + l];
            const int du = ks * 8 + q * 2;            // (d0>>2), d0 = ks*32+q*8
            const uint u0 = r2u[du], u1 = r2u[du + 1];
            v.x &= hm2(u0, 0);  v.y &= hm2(u0, 16);
            v.z &= hm2(u1, 0);  v.w &= hm2(u1, 16);
            BufV[id * 64 + l] = v;
        }
    }
    __syncthreads();

    // ---- GEMM1: A1^T = W2T @ Bf1 ; wave w owns rb in {4w..4w+3}, all cb
    f32x4 acc[4][4];                       // [rp][cb]
    #pragma unroll
    for (int rp = 0; rp < 4; ++rp)
        #pragma unroll
        for (int cb = 0; cb < 4; ++cb) acc[rp][cb] = (f32x4){0.f, 0.f, 0.f, 0.f};

    {
        const bf16x8* W2Tf = (const bf16x8*)(ws + W2TA_OFF);
        const bf16x8* BufF = (const bf16x8*)Buf;
        #pragma unroll 1
        for (int ks = 0; ks < 8; ++ks) {
            bf16x8 a[4];
            #pragma unroll
            for (int rp = 0; rp < 4; ++rp) a[rp] = W2Tf[((4 * w + rp) * 8 + ks) * 64 + l];
            #pragma unroll
            for (int cb = 0; cb < 4; ++cb) {
                const bf16x8 bb = BufF[(cb * 8 + ks) * 64 + l];
                #pragma unroll
                for (int rp = 0; rp < 4; ++rp)
                    acc[rp][cb] = __builtin_amdgcn_mfma_f32_16x16x32_bf16(a[rp], bb, acc[rp][cb], 0, 0, 0);
            }
        }
    }
    __syncthreads();   // all Bf1 reads done before Vh overlay

    // ---- Phase C: Vh[j][e] = A1^T[e][j] * r1[e] (bf16, XOR-swizzled, b64 writes)
    {
        ushort* Vh = (ushort*)Buf;
        #pragma unroll
        for (int rp = 0; rp < 4; ++rp) {
            const int rb = 4 * w + rp;
            const int e0 = rb * 16 + q * 4;
            const uint mu = r1u[rb * 4 + q];
            #pragma unroll
            for (int cb = 0; cb < 4; ++cb) {
                const f32x4 av = acc[rp][cb];
                const float v0 = (mu & 0xFFu)       ? av.x : 0.f;
                const float v1 = (mu & 0xFF00u)     ? av.y : 0.f;
                const float v2 = (mu & 0xFF0000u)   ? av.z : 0.f;
                const float v3 = (mu & 0xFF000000u) ? av.w : 0.f;
                u32x2 p;
                p.x = (uint)f2bf(v0) | ((uint)f2bf(v1) << 16);
                p.y = (uint)f2bf(v2) | ((uint)f2bf(v3) << 16);
                const int j = cb * 16 + m;
                const int idx = j * 256 + (e0 ^ ((j & 7) << 3));
                *(u32x2*)&Vh[idx] = p;
            }
        }
    }
    __syncthreads();

    // ---- GEMM2: M^T = W1T @ (Vh as B) ; wave w owns rb_n in {4w..4w+3}
    f32x4 acc2[4][4];
    #pragma unroll
    for (int rp = 0; rp < 4; ++rp)
        #pragma unroll
        for (int cb = 0; cb < 4; ++cb) acc2[rp][cb] = (f32x4){0.f, 0.f, 0.f, 0.f};

    {
        const bf16x8* W1Tf = (const bf16x8*)(ws + W1TA_OFF);
        const ushort* Vh = (const ushort*)Buf;
        #pragma unroll 1
        for (int ks = 0; ks < 8; ++ks) {
            bf16x8 a[4];
            #pragma unroll
            for (int rp = 0; rp < 4; ++rp) a[rp] = W1Tf[((4 * w + rp) * 8 + ks) * 64 + l];
            const int c0 = ks * 32 + q * 8;
            #pragma unroll
            for (int cb = 0; cb < 4; ++cb) {
                const int j = cb * 16 + m;
                const bf16x8 bb = *(const bf16x8*)&Vh[j * 256 + (c0 ^ ((j & 7) << 3))];
                #pragma unroll
                for (int rp = 0; rp < 4; ++rp)
                    acc2[rp][cb] = __builtin_amdgcn_mfma_f32_16x16x32_bf16(a[rp], bb, acc2[rp][cb], 0, 0, 0);
            }
        }
    }

    // ---- reduce ||M||_F^2
    {
        float ps = 0.f;
        #pragma unroll
        for (int rp = 0; rp < 4; ++rp)
            #pragma unroll
            for (int cb = 0; cb < 4; ++cb) {
                const f32x4 a0 = acc2[rp][cb];
                ps = fmaf(a0.x, a0.x, ps); ps = fmaf(a0.y, a0.y, ps);
                ps = fmaf(a0.z, a0.z, ps); ps = fmaf(a0.w, a0.w, ps);
            }
        #pragma unroll
        for (int off = 32; off > 0; off >>= 1) ps += __shfl_down(ps, off, 64);
        if (l == 0) red[w] = ps;
    }
    __syncthreads();

    if (t < 64) {
        const float S = red[0] + red[1] + red[2] + red[3];
        const float* fws = (const float*)(ws + F_OFF);
        const float f = fws[(size_t)b * 64 + t];
        const float kv = kp[0];
        const float ksp = fmaxf(kv, 0.0f) + log1pf(expf(-fabsf(kv)));
        out[(size_t)b * 64 + t] = tanhf(ksp * f / (sqrtf(S) + 1e-4f));
    }
}

extern "C" void kernel_launch(void* const* d_in, const int* in_sizes, int n_in,
                              void* d_out, int out_size, void* d_ws, size_t ws_size,
                              hipStream_t stream) {
    const float* x  = (const float*)d_in[0];
    const float* W1 = (const float*)d_in[1];
    const float* b1 = (const float*)d_in[2];
    const float* W2 = (const float*)d_in[3];
    const float* b2 = (const float*)d_in[4];
    const float* W3 = (const float*)d_in[5];
    const float* b3 = (const float*)d_in[6];
    const float* kp = (const float*)d_in[7];
    char* ws = (char*)d_ws;

    k0_prep<<<136, 256, 0, stream>>>(W1, W2, W3, ws);
    k1_forward<<<512, 512, 0, stream>>>(x, b1, b2, b3, ws);
    k2_jac<<<8192, 256, 0, stream>>>(ws, kp, (float*)d_out);
}

// Round 12
// 209.041 us; speedup vs baseline: 1.1309x; 1.0130x over previous
//
#include <hip/hip_runtime.h>
#include <math.h>

// LipsNet R12. B=8192, D_IN=256, H=256, D_OUT=64.
// k0: weight frags (R4/R7-validated layouts). [unchanged]
// k1: split-bf16 MFMA forward, R8-verbatim. [unchanged]
// k2: R11 structure (S=1, 256 thr, Phase-A pre-mask, 4 blocks/CU) with ONE change:
//     byte-masks expanded ONCE per block into halfword-mask LDS tables (r1m/r2m);
//     Phase A = b128 broadcast + 4 ANDs (was ~50 ops of hm2 per frag-unit);
//     Phase C = pack-then-AND (was 4 cndmask selects). Bit-identical numerics.
//
// MFMA 16x16x32 layouts (validated R2/R4):
//   A[m][k]: m = lane&15, k = (lane>>4)*8 + i
//   B[k][n]: n = lane&15, k = (lane>>4)*8 + i
//   C/D:     col = lane&15, row = (lane>>4)*4 + reg

typedef float  f32x4  __attribute__((ext_vector_type(4)));
typedef short  bf16x8 __attribute__((ext_vector_type(8)));
typedef unsigned int   uint;
typedef unsigned short ushort;
typedef unsigned char  uchar;
typedef uint   u32x4  __attribute__((ext_vector_type(4)));
typedef uint   u32x2  __attribute__((ext_vector_type(2)));

// ws byte offsets
#define W2TA_OFF 0u        // 16rb x 8ks x 64l x 16B = 131072
#define W1TA_OFF 131072u   // 131072
#define W3A_OFF  262144u   // 32768 (k2 B-source AND k1 layer-3 hi A-frags)
#define F_OFF    294912u   // 8192x64 fp32 = 2097152
#define R1_OFF   2392064u  // 8192x256 u8 = 2097152
#define R2_OFF   4489216u  // 2097152
#define W1AH_OFF 6586368u  // 131072
#define W1AL_OFF 6717440u  // 131072
#define W2AH_OFF 6848512u  // 131072
#define W2AL_OFF 6979584u  // 131072
#define W3AL_OFF 7110656u  // 32768
// total 7143424 B

__device__ __forceinline__ ushort f2bf(float f) {
    uint u = __builtin_bit_cast(uint, f);
    u += 0x7FFFu + ((u >> 16) & 1u);          // RNE
    return (ushort)(u >> 16);
}
__device__ __forceinline__ float bf2f(ushort h) {
    uint u = ((uint)h) << 16;
    return __builtin_bit_cast(float, u);
}
// halfword and-mask from two mask bytes of u at bit positions sh, sh+8
__device__ __forceinline__ uint hm2(uint u, int sh) {
    return (((u >> sh) & 0xFFu)   ? 0xFFFFu     : 0u) |
           (((u >> sh) & 0xFF00u) ? 0xFFFF0000u : 0u);
}

// ---------------- k0: weight prep (R7-validated) ----------------
__global__ __launch_bounds__(256) void k0_prep(
    const float* __restrict__ W1, const float* __restrict__ W2,
    const float* __restrict__ W3, char* __restrict__ ws)
{
    const int id = blockIdx.x * 256 + threadIdx.x;
    if (id >= 34816) return;

    if (id < 16384) {
        // transposed A-frag gathers for k2
        const int fid = id & 8191;
        const int l = fid & 63, ks = (fid >> 6) & 7, rb = fid >> 9;
        const int m = l & 15, q = l >> 4;
        const int k0 = ks * 32 + q * 8;
        const float* M = (id < 8192) ? W2 : W1;
        const uint dstoff = (id < 8192) ? W2TA_OFF : W1TA_OFF;
        const int n = rb * 16 + m;
        ushort h[8];
        #pragma unroll
        for (int i = 0; i < 8; ++i) h[i] = f2bf(M[(k0 + i) * 256 + n]);
        u32x4 v;
        v.x = (uint)h[0] | ((uint)h[1] << 16);
        v.y = (uint)h[2] | ((uint)h[3] << 16);
        v.z = (uint)h[4] | ((uint)h[5] << 16);
        v.w = (uint)h[6] | ((uint)h[7] << 16);
        ((u32x4*)(ws + dstoff))[fid] = v;
        return;
    }

    // hi/lo A-frag pairs (row-major gathers) for k1 forward
    const float* M;
    uint hiOff, loOff;
    int fid;
    if (id < 18432)      { fid = id - 16384; M = W3; hiOff = W3A_OFF;  loOff = W3AL_OFF; }
    else if (id < 26624) { fid = id - 18432; M = W1; hiOff = W1AH_OFF; loOff = W1AL_OFF; }
    else                 { fid = id - 26624; M = W2; hiOff = W2AH_OFF; loOff = W2AL_OFF; }
    const int l = fid & 63, ks = (fid >> 6) & 7, rb = fid >> 9;
    const int m = l & 15, q = l >> 4;
    const int k0 = ks * 32 + q * 8;
    const float* p = M + (rb * 16 + m) * 256 + k0;
    ushort hh[8], ll[8];
    #pragma unroll
    for (int i = 0; i < 8; ++i) {
        const float v = p[i];
        const ushort h = f2bf(v);
        hh[i] = h;
        ll[i] = f2bf(v - bf2f(h));     // residual (exact subtraction)
    }
    u32x4 vh, vl;
    vh.x = (uint)hh[0] | ((uint)hh[1] << 16);
    vh.y = (uint)hh[2] | ((uint)hh[3] << 16);
    vh.z = (uint)hh[4] | ((uint)hh[5] << 16);
    vh.w = (uint)hh[6] | ((uint)hh[7] << 16);
    vl.x = (uint)ll[0] | ((uint)ll[1] << 16);
    vl.y = (uint)ll[2] | ((uint)ll[3] << 16);
    vl.z = (uint)ll[4] | ((uint)ll[5] << 16);
    vl.w = (uint)ll[6] | ((uint)ll[7] << 16);
    ((u32x4*)(ws + hiOff))[fid] = vh;
    ((u32x4*)(ws + loOff))[fid] = vl;
}

// ---------------- k1: split-bf16 MFMA forward, 16 samples/block, 512 thr (R8-verbatim) ----------------
#define FWD_KLOOP(INOFF, HIOFF, LOOFF, NRB, RBOF, ACC)                             \
    {                                                                              \
        const bf16x8* WH = (const bf16x8*)(ws + (HIOFF));                          \
        const bf16x8* WL = (const bf16x8*)(ws + (LOOFF));                          \
        _Pragma("unroll")                                                          \
        for (int rr = 0; rr < (NRB); ++rr) ACC[rr] = (f32x4){0.f, 0.f, 0.f, 0.f};  \
        _Pragma("unroll")                                                          \
        for (int ks = 0; ks < 8; ++ks) {                                           \
            const int kk = ks * 32 + q * 8;                                        \
            float av[8];                                                           \
            *(f32x4*)&av[0] = *(const f32x4*)&SB[(INOFF) + m * 260 + kk];          \
            *(f32x4*)&av[4] = *(const f32x4*)&SB[(INOFF) + m * 260 + kk + 4];      \
            uint hw[4], lw[4];                                                     \
            _Pragma("unroll")                                                      \
            for (int pp = 0; pp < 4; ++pp) {                                       \
                const float a0 = av[2 * pp], a1 = av[2 * pp + 1];                  \
                const ushort h0 = f2bf(a0), h1 = f2bf(a1);                         \
                const float r0 = a0 - bf2f(h0), r1 = a1 - bf2f(h1);                \
                hw[pp] = (uint)h0 | ((uint)h1 << 16);                              \
                lw[pp] = (uint)f2bf(r0) | ((uint)f2bf(r1) << 16);                  \
            }                                                                      \
            const bf16x8 bhi = __builtin_bit_cast(bf16x8, (u32x4){hw[0], hw[1], hw[2], hw[3]}); \
            const bf16x8 blo = __builtin_bit_cast(bf16x8, (u32x4){lw[0], lw[1], lw[2], lw[3]}); \
            _Pragma("unroll")                                                      \
            for (int rr = 0; rr < (NRB); ++rr) {                                   \
                const int rb = (RBOF) + rr;                                        \
                const bf16x8 ah = WH[(rb * 8 + ks) * 64 + l];                      \
                const bf16x8 al = WL[(rb * 8 + ks) * 64 + l];                      \
                ACC[rr] = __builtin_amdgcn_mfma_f32_16x16x32_bf16(ah, bhi, ACC[rr], 0, 0, 0); \
                ACC[rr] = __builtin_amdgcn_mfma_f32_16x16x32_bf16(al, bhi, ACC[rr], 0, 0, 0); \
                ACC[rr] = __builtin_amdgcn_mfma_f32_16x16x32_bf16(ah, blo, ACC[rr], 0, 0, 0); \
            }                                                                      \
        }                                                                          \
    }

__global__ __launch_bounds__(512) void k1_forward(
    const float* __restrict__ x,
    const float* __restrict__ b1, const float* __restrict__ b2,
    const float* __restrict__ b3, char* __restrict__ ws)
{
    __shared__ float SB[2 * 4160];   // [2][16 samples][260 fp32]; buf0: x then h2, buf1: h1
    const int t = threadIdx.x, w = t >> 6, l = t & 63;
    const int m = l & 15, q = l >> 4;
    const int g0 = blockIdx.x * 16;
    float* fws = (float*)(ws + F_OFF);
    uchar* r1g = (uchar*)(ws + R1_OFF);
    uchar* r2g = (uchar*)(ws + R2_OFF);

    {
        const f32x4* X4 = (const f32x4*)x;
        #pragma unroll
        for (int i = 0; i < 2; ++i) {
            const int idx = t + 512 * i;            // 0..1023
            const int g = idx >> 6, dq = idx & 63;
            *(f32x4*)&SB[g * 260 + dq * 4] = X4[(size_t)(g0 + g) * 64 + dq];
        }
    }
    __syncthreads();

    f32x4 acc[2];

    // ---- layer 1
    FWD_KLOOP(0, W1AH_OFF, W1AL_OFF, 2, 2 * w, acc)
    #pragma unroll
    for (int rr = 0; rr < 2; ++rr) {
        const int i0 = (2 * w + rr) * 16 + q * 4;
        const float4 bv = *(const float4*)(b1 + i0);
        const float v0 = acc[rr].x + bv.x, v1 = acc[rr].y + bv.y;
        const float v2 = acc[rr].z + bv.z, v3 = acc[rr].w + bv.w;
        const uint mv = (v0 > 0.f ? 1u : 0u) | (v1 > 0.f ? 0x100u : 0u) |
                        (v2 > 0.f ? 0x10000u : 0u) | (v3 > 0.f ? 0x1000000u : 0u);
        *(uint*)(r1g + (size_t)(g0 + m) * 256 + i0) = mv;
        const f32x4 rv = {fmaxf(v0, 0.f), fmaxf(v1, 0.f), fmaxf(v2, 0.f), fmaxf(v3, 0.f)};
        *(f32x4*)&SB[4160 + m * 260 + i0] = rv;
    }
    __syncthreads();

    // ---- layer 2
    FWD_KLOOP(4160, W2AH_OFF, W2AL_OFF, 2, 2 * w, acc)
    #pragma unroll
    for (int rr = 0; rr < 2; ++rr) {
        const int i0 = (2 * w + rr) * 16 + q * 4;
        const float4 bv = *(const float4*)(b2 + i0);
        const float v0 = acc[rr].x + bv.x, v1 = acc[rr].y + bv.y;
        const float v2 = acc[rr].z + bv.z, v3 = acc[rr].w + bv.w;
        const uint mv = (v0 > 0.f ? 1u : 0u) | (v1 > 0.f ? 0x100u : 0u) |
                        (v2 > 0.f ? 0x10000u : 0u) | (v3 > 0.f ? 0x1000000u : 0u);
        *(uint*)(r2g + (size_t)(g0 + m) * 256 + i0) = mv;
        const f32x4 rv = {fmaxf(v0, 0.f), fmaxf(v1, 0.f), fmaxf(v2, 0.f), fmaxf(v3, 0.f)};
        *(f32x4*)&SB[m * 260 + i0] = rv;
    }
    __syncthreads();

    // ---- layer 3: waves 0..3
    if (w < 4) {
        FWD_KLOOP(0, W3A_OFF, W3AL_OFF, 1, w, acc)
        const int j0 = w * 16 + q * 4;
        const float4 bv = *(const float4*)(b3 + j0);
        const f32x4 ov = {acc[0].x + bv.x, acc[0].y + bv.y, acc[0].z + bv.z, acc[0].w + bv.w};
        *(f32x4*)(fws + (size_t)(g0 + m) * 64 + j0) = ov;
    }
}

// ---------------- k2: Jacobian, 1 sample/block, 256 thr, halfword-mask LDS tables ----------------
__global__ __launch_bounds__(256, 4) void k2_jac(
    const char* __restrict__ ws, const float* __restrict__ kp,
    float* __restrict__ out)
{
    __shared__ char Buf[32768];            // Phase A: masked W3 B-frags; then Vh overlay
    __shared__ uint r1m[128], r2m[128];    // halfword masks: r*m[i] covers elements 2i, 2i+1
    __shared__ float red[4];

    const int t = threadIdx.x, w = t >> 6, l = t & 63;
    const int m = l & 15, q = l >> 4;
    const int b = blockIdx.x;

    // one-time mask expansion: 4 byte-masks -> 2 halfword-mask words per thread
    if (t < 64) {
        const uint u = ((const uint*)(ws + R1_OFF))[(size_t)b * 64 + t];
        r1m[2 * t]     = hm2(u, 0);
        r1m[2 * t + 1] = hm2(u, 16);
    } else if (t < 128) {
        const uint u = ((const uint*)(ws + R2_OFF))[(size_t)b * 64 + (t - 64)];
        r2m[2 * (t - 64)]     = hm2(u, 0);
        r2m[2 * (t - 64) + 1] = hm2(u, 16);
    }
    __syncthreads();

    // ---- Phase A: Bf1 = (W3 .* r2)^T B-frags; b128 mask broadcast + 4 ANDs per unit
    {
        const u32x4* W3Av = (const u32x4*)(ws + W3A_OFF);
        u32x4* BufV = (u32x4*)Buf;
        #pragma unroll
        for (int ii = 0; ii < 8; ++ii) {
            const int id = w * 8 + ii;                // 0..31: cb = id>>3, ks = id&7
            const int ks = id & 7;
            u32x4 v = W3Av[id * 64 + l];
            const u32x4 mk = *(const u32x4*)&r2m[ks * 16 + q * 4];  // (d0>>1), d0=ks*32+q*8
            v.x &= mk.x; v.y &= mk.y; v.z &= mk.z; v.w &= mk.w;
            BufV[id * 64 + l] = v;
        }
    }
    __syncthreads();

    // ---- GEMM1: A1^T = W2T @ Bf1 ; wave w owns rb in {4w..4w+3}, all cb
    f32x4 acc[4][4];                       // [rp][cb]
    #pragma unroll
    for (int rp = 0; rp < 4; ++rp)
        #pragma unroll
        for (int cb = 0; cb < 4; ++cb) acc[rp][cb] = (f32x4){0.f, 0.f, 0.f, 0.f};

    {
        const bf16x8* W2Tf = (const bf16x8*)(ws + W2TA_OFF);
        const bf16x8* BufF = (const bf16x8*)Buf;
        #pragma unroll 1
        for (int ks = 0; ks < 8; ++ks) {
            bf16x8 a[4];
            #pragma unroll
            for (int rp = 0; rp < 4; ++rp) a[rp] = W2Tf[((4 * w + rp) * 8 + ks) * 64 + l];
            #pragma unroll
            for (int cb = 0; cb < 4; ++cb) {
                const bf16x8 bb = BufF[(cb * 8 + ks) * 64 + l];
                #pragma unroll
                for (int rp = 0; rp < 4; ++rp)
                    acc[rp][cb] = __builtin_amdgcn_mfma_f32_16x16x32_bf16(a[rp], bb, acc[rp][cb], 0, 0, 0);
            }
        }
    }
    __syncthreads();   // all Bf1 reads done before Vh overlay

    // ---- Phase C: Vh[j][e] = A1^T[e][j] * r1[e]; pack then AND (bit-identical to select)
    {
        ushort* Vh = (ushort*)Buf;
        #pragma unroll
        for (int rp = 0; rp < 4; ++rp) {
            const int rb = 4 * w + rp;
            const int e0 = rb * 16 + q * 4;
            const u32x2 mk = *(const u32x2*)&r1m[rb * 8 + q * 2];   // (e0>>1)
            #pragma unroll
            for (int cb = 0; cb < 4; ++cb) {
                const f32x4 av = acc[rp][cb];
                u32x2 p;
                p.x = ((uint)f2bf(av.x) | ((uint)f2bf(av.y) << 16)) & mk.x;
                p.y = ((uint)f2bf(av.z) | ((uint)f2bf(av.w) << 16)) & mk.y;
                const int j = cb * 16 + m;
                const int idx = j * 256 + (e0 ^ ((j & 7) << 3));
                *(u32x2*)&Vh[idx] = p;
            }
        }
    }
    __syncthreads();

    // ---- GEMM2: M^T = W1T @ (Vh as B) ; wave w owns rb_n in {4w..4w+3}
    f32x4 acc2[4][4];
    #pragma unroll
    for (int rp = 0; rp < 4; ++rp)
        #pragma unroll
        for (int cb = 0; cb < 4; ++cb) acc2[rp][cb] = (f32x4){0.f, 0.f, 0.f, 0.f};

    {
        const bf16x8* W1Tf = (const bf16x8*)(ws + W1TA_OFF);
        const ushort* Vh = (const ushort*)Buf;
        #pragma unroll 1
        for (int ks = 0; ks < 8; ++ks) {
            bf16x8 a[4];
            #pragma unroll
            for (int rp = 0; rp < 4; ++rp) a[rp] = W1Tf[((4 * w + rp) * 8 + ks) * 64 + l];
            const int c0 = ks * 32 + q * 8;
            #pragma unroll
            for (int cb = 0; cb < 4; ++cb) {
                const int j = cb * 16 + m;
                const bf16x8 bb = *(const bf16x8*)&Vh[j * 256 + (c0 ^ ((j & 7) << 3))];
                #pragma unroll
                for (int rp = 0; rp < 4; ++rp)
                    acc2[rp][cb] = __builtin_amdgcn_mfma_f32_16x16x32_bf16(a[rp], bb, acc2[rp][cb], 0, 0, 0);
            }
        }
    }

    // ---- reduce ||M||_F^2
    {
        float ps = 0.f;
        #pragma unroll
        for (int rp = 0; rp < 4; ++rp)
            #pragma unroll
            for (int cb = 0; cb < 4; ++cb) {
                const f32x4 a0 = acc2[rp][cb];
                ps = fmaf(a0.x, a0.x, ps); ps = fmaf(a0.y, a0.y, ps);
                ps = fmaf(a0.z, a0.z, ps); ps = fmaf(a0.w, a0.w, ps);
            }
        #pragma unroll
        for (int off = 32; off > 0; off >>= 1) ps += __shfl_down(ps, off, 64);
        if (l == 0) red[w] = ps;
    }
    __syncthreads();

    if (t < 64) {
        const float S = red[0] + red[1] + red[2] + red[3];
        const float* fws = (const float*)(ws + F_OFF);
        const float f = fws[(size_t)b * 64 + t];
        const float kv = kp[0];
        const float ksp = fmaxf(kv, 0.0f) + log1pf(expf(-fabsf(kv)));
        out[(size_t)b * 64 + t] = tanhf(ksp * f / (sqrtf(S) + 1e-4f));
    }
}

extern "C" void kernel_launch(void* const* d_in, const int* in_sizes, int n_in,
                              void* d_out, int out_size, void* d_ws, size_t ws_size,
                              hipStream_t stream) {
    const float* x  = (const float*)d_in[0];
    const float* W1 = (const float*)d_in[1];
    const float* b1 = (const float*)d_in[2];
    const float* W2 = (const float*)d_in[3];
    const float* b2 = (const float*)d_in[4];
    const float* W3 = (const float*)d_in[5];
    const float* b3 = (const float*)d_in[6];
    const float* kp = (const float*)d_in[7];
    char* ws = (char*)d_ws;

    k0_prep<<<136, 256, 0, stream>>>(W1, W2, W3, ws);
    k1_forward<<<512, 512, 0, stream>>>(x, b1, b2, b3, ws);
    k2_jac<<<8192, 256, 0, stream>>>(ws, kp, (float*)d_out);
}

// Round 13
// 205.462 us; speedup vs baseline: 1.1506x; 1.0174x over previous
//
#include <hip/hip_runtime.h>
#include <math.h>

// LipsNet R13. B=8192, D_IN=256, H=256, D_OUT=64.
// k0: weight frags (R4/R7-validated layouts). [unchanged]
// k2: R12-verbatim (plateaued at ~128 us, 1.94x MFMA floor). [unchanged]
// k1: activations stored as PRE-SPLIT hi/lo bf16 planes in LDS (converted once at
//     epilogue, bit-identical values) -> K-loop = 2 ds_read_b128 + 6 MFMA, killing
//     the 8-way-redundant in-loop split conversion (~60% of k1's VALU).
//
// MFMA 16x16x32 layouts (validated R2/R4):
//   A[m][k]: m = lane&15, k = (lane>>4)*8 + i
//   B[k][n]: n = lane&15, k = (lane>>4)*8 + i
//   C/D:     col = lane&15, row = (lane>>4)*4 + reg

typedef float  f32x4  __attribute__((ext_vector_type(4)));
typedef short  bf16x8 __attribute__((ext_vector_type(8)));
typedef unsigned int   uint;
typedef unsigned short ushort;
typedef unsigned char  uchar;
typedef uint   u32x4  __attribute__((ext_vector_type(4)));
typedef uint   u32x2  __attribute__((ext_vector_type(2)));

// ws byte offsets
#define W2TA_OFF 0u        // 16rb x 8ks x 64l x 16B = 131072
#define W1TA_OFF 131072u   // 131072
#define W3A_OFF  262144u   // 32768 (k2 B-source AND k1 layer-3 hi A-frags)
#define F_OFF    294912u   // 8192x64 fp32 = 2097152
#define R1_OFF   2392064u  // 8192x256 u8 = 2097152
#define R2_OFF   4489216u  // 2097152
#define W1AH_OFF 6586368u  // 131072
#define W1AL_OFF 6717440u  // 131072
#define W2AH_OFF 6848512u  // 131072
#define W2AL_OFF 6979584u  // 131072
#define W3AL_OFF 7110656u  // 32768
// total 7143424 B

__device__ __forceinline__ ushort f2bf(float f) {
    uint u = __builtin_bit_cast(uint, f);
    u += 0x7FFFu + ((u >> 16) & 1u);          // RNE
    return (ushort)(u >> 16);
}
__device__ __forceinline__ float bf2f(ushort h) {
    uint u = ((uint)h) << 16;
    return __builtin_bit_cast(float, u);
}
// halfword and-mask from two mask bytes of u at bit positions sh, sh+8
__device__ __forceinline__ uint hm2(uint u, int sh) {
    return (((u >> sh) & 0xFFu)   ? 0xFFFFu     : 0u) |
           (((u >> sh) & 0xFF00u) ? 0xFFFF0000u : 0u);
}

// ---------------- k0: weight prep (R7-validated) ----------------
__global__ __launch_bounds__(256) void k0_prep(
    const float* __restrict__ W1, const float* __restrict__ W2,
    const float* __restrict__ W3, char* __restrict__ ws)
{
    const int id = blockIdx.x * 256 + threadIdx.x;
    if (id >= 34816) return;

    if (id < 16384) {
        // transposed A-frag gathers for k2
        const int fid = id & 8191;
        const int l = fid & 63, ks = (fid >> 6) & 7, rb = fid >> 9;
        const int m = l & 15, q = l >> 4;
        const int k0 = ks * 32 + q * 8;
        const float* M = (id < 8192) ? W2 : W1;
        const uint dstoff = (id < 8192) ? W2TA_OFF : W1TA_OFF;
        const int n = rb * 16 + m;
        ushort h[8];
        #pragma unroll
        for (int i = 0; i < 8; ++i) h[i] = f2bf(M[(k0 + i) * 256 + n]);
        u32x4 v;
        v.x = (uint)h[0] | ((uint)h[1] << 16);
        v.y = (uint)h[2] | ((uint)h[3] << 16);
        v.z = (uint)h[4] | ((uint)h[5] << 16);
        v.w = (uint)h[6] | ((uint)h[7] << 16);
        ((u32x4*)(ws + dstoff))[fid] = v;
        return;
    }

    // hi/lo A-frag pairs (row-major gathers) for k1 forward
    const float* M;
    uint hiOff, loOff;
    int fid;
    if (id < 18432)      { fid = id - 16384; M = W3; hiOff = W3A_OFF;  loOff = W3AL_OFF; }
    else if (id < 26624) { fid = id - 18432; M = W1; hiOff = W1AH_OFF; loOff = W1AL_OFF; }
    else                 { fid = id - 26624; M = W2; hiOff = W2AH_OFF; loOff = W2AL_OFF; }
    const int l = fid & 63, ks = (fid >> 6) & 7, rb = fid >> 9;
    const int m = l & 15, q = l >> 4;
    const int k0 = ks * 32 + q * 8;
    const float* p = M + (rb * 16 + m) * 256 + k0;
    ushort hh[8], ll[8];
    #pragma unroll
    for (int i = 0; i < 8; ++i) {
        const float v = p[i];
        const ushort h = f2bf(v);
        hh[i] = h;
        ll[i] = f2bf(v - bf2f(h));     // residual (exact subtraction)
    }
    u32x4 vh, vl;
    vh.x = (uint)hh[0] | ((uint)hh[1] << 16);
    vh.y = (uint)hh[2] | ((uint)hh[3] << 16);
    vh.z = (uint)hh[4] | ((uint)hh[5] << 16);
    vh.w = (uint)hh[6] | ((uint)hh[7] << 16);
    vl.x = (uint)ll[0] | ((uint)ll[1] << 16);
    vl.y = (uint)ll[2] | ((uint)ll[3] << 16);
    vl.z = (uint)ll[4] | ((uint)ll[5] << 16);
    vl.w = (uint)ll[6] | ((uint)ll[7] << 16);
    ((u32x4*)(ws + hiOff))[fid] = vh;
    ((u32x4*)(ws + loOff))[fid] = vl;
}

// ---------------- k1: split-plane MFMA forward, 16 samples/block, 512 thr ----------------
// Activations in LDS as hi/lo bf16 planes [buf][16][264]; K-loop: 2 b128 reads + 6 MFMA/ks.
#define FWD_KLOOP2(BUF, HIOFF, LOOFF, NRB, RBOF, ACC)                              \
    {                                                                              \
        const bf16x8* WH = (const bf16x8*)(ws + (HIOFF));                          \
        const bf16x8* WL = (const bf16x8*)(ws + (LOOFF));                          \
        _Pragma("unroll")                                                          \
        for (int rr = 0; rr < (NRB); ++rr) ACC[rr] = (f32x4){0.f, 0.f, 0.f, 0.f};  \
        _Pragma("unroll")                                                          \
        for (int ks = 0; ks < 8; ++ks) {                                           \
            const int kk = ks * 32 + q * 8;                                        \
            const bf16x8 bhi = *(const bf16x8*)&HP[BUF][m][kk];                    \
            const bf16x8 blo = *(const bf16x8*)&LP[BUF][m][kk];                    \
            _Pragma("unroll")                                                      \
            for (int rr = 0; rr < (NRB); ++rr) {                                   \
                const int rb = (RBOF) + rr;                                        \
                const bf16x8 ah = WH[(rb * 8 + ks) * 64 + l];                      \
                const bf16x8 al = WL[(rb * 8 + ks) * 64 + l];                      \
                ACC[rr] = __builtin_amdgcn_mfma_f32_16x16x32_bf16(ah, bhi, ACC[rr], 0, 0, 0); \
                ACC[rr] = __builtin_amdgcn_mfma_f32_16x16x32_bf16(al, bhi, ACC[rr], 0, 0, 0); \
                ACC[rr] = __builtin_amdgcn_mfma_f32_16x16x32_bf16(ah, blo, ACC[rr], 0, 0, 0); \
            }                                                                      \
        }                                                                          \
    }

__global__ __launch_bounds__(512) void k1_forward(
    const float* __restrict__ x,
    const float* __restrict__ b1, const float* __restrict__ b2,
    const float* __restrict__ b3, char* __restrict__ ws)
{
    __shared__ ushort HP[2][16][264];   // hi planes: buf0 = x then h2, buf1 = h1
    __shared__ ushort LP[2][16][264];   // lo planes
    const int t = threadIdx.x, w = t >> 6, l = t & 63;
    const int m = l & 15, q = l >> 4;
    const int g0 = blockIdx.x * 16;
    float* fws = (float*)(ws + F_OFF);
    uchar* r1g = (uchar*)(ws + R1_OFF);
    uchar* r2g = (uchar*)(ws + R2_OFF);

    // stage x (coalesced), split once into hi/lo planes of buf0
    {
        const f32x4* X4 = (const f32x4*)x;
        #pragma unroll
        for (int i = 0; i < 2; ++i) {
            const int idx = t + 512 * i;            // 0..1023
            const int g = idx >> 6, dq = idx & 63;
            const f32x4 xv = X4[(size_t)(g0 + g) * 64 + dq];
            ushort h[4], lo[4];
            #pragma unroll
            for (int p = 0; p < 4; ++p) {
                const float v = xv[p];
                h[p] = f2bf(v);
                lo[p] = f2bf(v - bf2f(h[p]));
            }
            u32x2 ph, pl;
            ph.x = (uint)h[0] | ((uint)h[1] << 16);
            ph.y = (uint)h[2] | ((uint)h[3] << 16);
            pl.x = (uint)lo[0] | ((uint)lo[1] << 16);
            pl.y = (uint)lo[2] | ((uint)lo[3] << 16);
            *(u32x2*)&HP[0][g][dq * 4] = ph;
            *(u32x2*)&LP[0][g][dq * 4] = pl;
        }
    }
    __syncthreads();

    f32x4 acc[2];

    // ---- layer 1: h1 = relu(W1 @ x) -> buf1 planes; masks r1
    FWD_KLOOP2(0, W1AH_OFF, W1AL_OFF, 2, 2 * w, acc)
    #pragma unroll
    for (int rr = 0; rr < 2; ++rr) {
        const int i0 = (2 * w + rr) * 16 + q * 4;
        const float4 bv = *(const float4*)(b1 + i0);
        const float v0 = acc[rr].x + bv.x, v1 = acc[rr].y + bv.y;
        const float v2 = acc[rr].z + bv.z, v3 = acc[rr].w + bv.w;
        const uint mv = (v0 > 0.f ? 1u : 0u) | (v1 > 0.f ? 0x100u : 0u) |
                        (v2 > 0.f ? 0x10000u : 0u) | (v3 > 0.f ? 0x1000000u : 0u);
        *(uint*)(r1g + (size_t)(g0 + m) * 256 + i0) = mv;
        const float r0 = fmaxf(v0, 0.f), r1 = fmaxf(v1, 0.f);
        const float r2 = fmaxf(v2, 0.f), r3 = fmaxf(v3, 0.f);
        const ushort h0 = f2bf(r0), h1 = f2bf(r1), h2 = f2bf(r2), h3 = f2bf(r3);
        u32x2 ph, pl;
        ph.x = (uint)h0 | ((uint)h1 << 16);
        ph.y = (uint)h2 | ((uint)h3 << 16);
        pl.x = (uint)f2bf(r0 - bf2f(h0)) | ((uint)f2bf(r1 - bf2f(h1)) << 16);
        pl.y = (uint)f2bf(r2 - bf2f(h2)) | ((uint)f2bf(r3 - bf2f(h3)) << 16);
        *(u32x2*)&HP[1][m][i0] = ph;
        *(u32x2*)&LP[1][m][i0] = pl;
    }
    __syncthreads();

    // ---- layer 2: h2 = relu(W2 @ h1) -> buf0 planes (overlay x); masks r2
    FWD_KLOOP2(1, W2AH_OFF, W2AL_OFF, 2, 2 * w, acc)
    #pragma unroll
    for (int rr = 0; rr < 2; ++rr) {
        const int i0 = (2 * w + rr) * 16 + q * 4;
        const float4 bv = *(const float4*)(b2 + i0);
        const float v0 = acc[rr].x + bv.x, v1 = acc[rr].y + bv.y;
        const float v2 = acc[rr].z + bv.z, v3 = acc[rr].w + bv.w;
        const uint mv = (v0 > 0.f ? 1u : 0u) | (v1 > 0.f ? 0x100u : 0u) |
                        (v2 > 0.f ? 0x10000u : 0u) | (v3 > 0.f ? 0x1000000u : 0u);
        *(uint*)(r2g + (size_t)(g0 + m) * 256 + i0) = mv;
        const float r0 = fmaxf(v0, 0.f), r1 = fmaxf(v1, 0.f);
        const float r2 = fmaxf(v2, 0.f), r3 = fmaxf(v3, 0.f);
        const ushort h0 = f2bf(r0), h1 = f2bf(r1), h2 = f2bf(r2), h3 = f2bf(r3);
        u32x2 ph, pl;
        ph.x = (uint)h0 | ((uint)h1 << 16);
        ph.y = (uint)h2 | ((uint)h3 << 16);
        pl.x = (uint)f2bf(r0 - bf2f(h0)) | ((uint)f2bf(r1 - bf2f(h1)) << 16);
        pl.y = (uint)f2bf(r2 - bf2f(h2)) | ((uint)f2bf(r3 - bf2f(h3)) << 16);
        *(u32x2*)&HP[0][m][i0] = ph;
        *(u32x2*)&LP[0][m][i0] = pl;
    }
    __syncthreads();

    // ---- layer 3: f = W3 @ h2 ; waves 0..3
    if (w < 4) {
        FWD_KLOOP2(0, W3A_OFF, W3AL_OFF, 1, w, acc)
        const int j0 = w * 16 + q * 4;
        const float4 bv = *(const float4*)(b3 + j0);
        const f32x4 ov = {acc[0].x + bv.x, acc[0].y + bv.y, acc[0].z + bv.z, acc[0].w + bv.w};
        *(f32x4*)(fws + (size_t)(g0 + m) * 64 + j0) = ov;
    }
}

// ---------------- k2: Jacobian, 1 sample/block, 256 thr (R12-verbatim) ----------------
__global__ __launch_bounds__(256, 4) void k2_jac(
    const char* __restrict__ ws, const float* __restrict__ kp,
    float* __restrict__ out)
{
    __shared__ char Buf[32768];            // Phase A: masked W3 B-frags; then Vh overlay
    __shared__ uint r1m[128], r2m[128];    // halfword masks: r*m[i] covers elements 2i, 2i+1
    __shared__ float red[4];

    const int t = threadIdx.x, w = t >> 6, l = t & 63;
    const int m = l & 15, q = l >> 4;
    const int b = blockIdx.x;

    if (t < 64) {
        const uint u = ((const uint*)(ws + R1_OFF))[(size_t)b * 64 + t];
        r1m[2 * t]     = hm2(u, 0);
        r1m[2 * t + 1] = hm2(u, 16);
    } else if (t < 128) {
        const uint u = ((const uint*)(ws + R2_OFF))[(size_t)b * 64 + (t - 64)];
        r2m[2 * (t - 64)]     = hm2(u, 0);
        r2m[2 * (t - 64) + 1] = hm2(u, 16);
    }
    __syncthreads();

    // ---- Phase A: Bf1 = (W3 .* r2)^T B-frags; b128 mask broadcast + 4 ANDs per unit
    {
        const u32x4* W3Av = (const u32x4*)(ws + W3A_OFF);
        u32x4* BufV = (u32x4*)Buf;
        #pragma unroll
        for (int ii = 0; ii < 8; ++ii) {
            const int id = w * 8 + ii;                // 0..31: cb = id>>3, ks = id&7
            const int ks = id & 7;
            u32x4 v = W3Av[id * 64 + l];
            const u32x4 mk = *(const u32x4*)&r2m[ks * 16 + q * 4];  // (d0>>1), d0=ks*32+q*8
            v.x &= mk.x; v.y &= mk.y; v.z &= mk.z; v.w &= mk.w;
            BufV[id * 64 + l] = v;
        }
    }
    __syncthreads();

    // ---- GEMM1: A1^T = W2T @ Bf1 ; wave w owns rb in {4w..4w+3}, all cb
    f32x4 acc[4][4];                       // [rp][cb]
    #pragma unroll
    for (int rp = 0; rp < 4; ++rp)
        #pragma unroll
        for (int cb = 0; cb < 4; ++cb) acc[rp][cb] = (f32x4){0.f, 0.f, 0.f, 0.f};

    {
        const bf16x8* W2Tf = (const bf16x8*)(ws + W2TA_OFF);
        const bf16x8* BufF = (const bf16x8*)Buf;
        #pragma unroll 1
        for (int ks = 0; ks < 8; ++ks) {
            bf16x8 a[4];
            #pragma unroll
            for (int rp = 0; rp < 4; ++rp) a[rp] = W2Tf[((4 * w + rp) * 8 + ks) * 64 + l];
            #pragma unroll
            for (int cb = 0; cb < 4; ++cb) {
                const bf16x8 bb = BufF[(cb * 8 + ks) * 64 + l];
                #pragma unroll
                for (int rp = 0; rp < 4; ++rp)
                    acc[rp][cb] = __builtin_amdgcn_mfma_f32_16x16x32_bf16(a[rp], bb, acc[rp][cb], 0, 0, 0);
            }
        }
    }
    __syncthreads();   // all Bf1 reads done before Vh overlay

    // ---- Phase C: Vh[j][e] = A1^T[e][j] * r1[e]; pack then AND (bit-identical to select)
    {
        ushort* Vh = (ushort*)Buf;
        #pragma unroll
        for (int rp = 0; rp < 4; ++rp) {
            const int rb = 4 * w + rp;
            const int e0 = rb * 16 + q * 4;
            const u32x2 mk = *(const u32x2*)&r1m[rb * 8 + q * 2];   // (e0>>1)
            #pragma unroll
            for (int cb = 0; cb < 4; ++cb) {
                const f32x4 av = acc[rp][cb];
                u32x2 p;
                p.x = ((uint)f2bf(av.x) | ((uint)f2bf(av.y) << 16)) & mk.x;
                p.y = ((uint)f2bf(av.z) | ((uint)f2bf(av.w) << 16)) & mk.y;
                const int j = cb * 16 + m;
                const int idx = j * 256 + (e0 ^ ((j & 7) << 3));
                *(u32x2*)&Vh[idx] = p;
            }
        }
    }
    __syncthreads();

    // ---- GEMM2: M^T = W1T @ (Vh as B) ; wave w owns rb_n in {4w..4w+3}
    f32x4 acc2[4][4];
    #pragma unroll
    for (int rp = 0; rp < 4; ++rp)
        #pragma unroll
        for (int cb = 0; cb < 4; ++cb) acc2[rp][cb] = (f32x4){0.f, 0.f, 0.f, 0.f};

    {
        const bf16x8* W1Tf = (const bf16x8*)(ws + W1TA_OFF);
        const ushort* Vh = (const ushort*)Buf;
        #pragma unroll 1
        for (int ks = 0; ks < 8; ++ks) {
            bf16x8 a[4];
            #pragma unroll
            for (int rp = 0; rp < 4; ++rp) a[rp] = W1Tf[((4 * w + rp) * 8 + ks) * 64 + l];
            const int c0 = ks * 32 + q * 8;
            #pragma unroll
            for (int cb = 0; cb < 4; ++cb) {
                const int j = cb * 16 + m;
                const bf16x8 bb = *(const bf16x8*)&Vh[j * 256 + (c0 ^ ((j & 7) << 3))];
                #pragma unroll
                for (int rp = 0; rp < 4; ++rp)
                    acc2[rp][cb] = __builtin_amdgcn_mfma_f32_16x16x32_bf16(a[rp], bb, acc2[rp][cb], 0, 0, 0);
            }
        }
    }

    // ---- reduce ||M||_F^2
    {
        float ps = 0.f;
        #pragma unroll
        for (int rp = 0; rp < 4; ++rp)
            #pragma unroll
            for (int cb = 0; cb < 4; ++cb) {
                const f32x4 a0 = acc2[rp][cb];
                ps = fmaf(a0.x, a0.x, ps); ps = fmaf(a0.y, a0.y, ps);
                ps = fmaf(a0.z, a0.z, ps); ps = fmaf(a0.w, a0.w, ps);
            }
        #pragma unroll
        for (int off = 32; off > 0; off >>= 1) ps += __shfl_down(ps, off, 64);
        if (l == 0) red[w] = ps;
    }
    __syncthreads();

    if (t < 64) {
        const float S = red[0] + red[1] + red[2] + red[3];
        const float* fws = (const float*)(ws + F_OFF);
        const float f = fws[(size_t)b * 64 + t];
        const float kv = kp[0];
        const float ksp = fmaxf(kv, 0.0f) + log1pf(expf(-fabsf(kv)));
        out[(size_t)b * 64 + t] = tanhf(ksp * f / (sqrtf(S) + 1e-4f));
    }
}

extern "C" void kernel_launch(void* const* d_in, const int* in_sizes, int n_in,
                              void* d_out, int out_size, void* d_ws, size_t ws_size,
                              hipStream_t stream) {
    const float* x  = (const float*)d_in[0];
    const float* W1 = (const float*)d_in[1];
    const float* b1 = (const float*)d_in[2];
    const float* W2 = (const float*)d_in[3];
    const float* b2 = (const float*)d_in[4];
    const float* W3 = (const float*)d_in[5];
    const float* b3 = (const float*)d_in[6];
    const float* kp = (const float*)d_in[7];
    char* ws = (char*)d_ws;

    k0_prep<<<136, 256, 0, stream>>>(W1, W2, W3, ws);
    k1_forward<<<512, 512, 0, stream>>>(x, b1, b2, b3, ws);
    k2_jac<<<8192, 256, 0, stream>>>(ws, kp, (float*)d_out);
}